// Round 1
// baseline (250.857 us; speedup 1.0000x reference)
//
#include <hip/hip_runtime.h>

// XGate(s=1, index=3, dim=3, N=14), batch=8, fp32.
// out.reshape(L,DIM,R,B)[l,j,r,b] = x.reshape(L,DIM,R,B)[l,(j-1)%3,r,b]
// Each (l,j) slab is a contiguous run of R*B floats -> permuted memcpy.

constexpr int DIMQ   = 3;
constexpr int LBLK   = 27;               // 3^3
constexpr int RBLK   = 59049;            // 3^10
constexpr int BATCH  = 8;
constexpr int CHUNK_F = RBLK * BATCH;    // 472392 floats per (l,j) slab
constexpr int CHUNK_V = CHUNK_F / 4;     // 118098 float4 per slab (16B-aligned)
constexpr int NCHUNK  = LBLK * DIMQ;     // 81 slabs

__global__ __launch_bounds__(256) void xgate_roll_kernel(
        const float4* __restrict__ in, float4* __restrict__ out) {
    const int v = blockIdx.x * blockDim.x + threadIdx.x;
    if (v >= CHUNK_V) return;
    const int chunk = blockIdx.y;            // destination slab = l*3 + j
    const int l = chunk / 3;
    const int j = chunk - l * 3;
    int jsrc = j + 2;                        // (j - 1) mod 3
    if (jsrc >= 3) jsrc -= 3;
    const int src_chunk = l * 3 + jsrc;
    out[(size_t)chunk * CHUNK_V + v] = in[(size_t)src_chunk * CHUNK_V + v];
}

extern "C" void kernel_launch(void* const* d_in, const int* in_sizes, int n_in,
                              void* d_out, int out_size, void* d_ws, size_t ws_size,
                              hipStream_t stream) {
    const float4* x = (const float4*)d_in[0];
    float4* out = (float4*)d_out;
    dim3 block(256);
    dim3 grid((CHUNK_V + 255) / 256, NCHUNK);
    xgate_roll_kernel<<<grid, block, 0, stream>>>(x, out);
}

// Round 2
// 247.594 us; speedup vs baseline: 1.0132x; 1.0132x over previous
//
#include <hip/hip_runtime.h>

// XGate(s=1, index=3, dim=3, N=14), batch=8, fp32.
// out.reshape(L,DIM,R,B)[l,j,r,b] = x.reshape(L,DIM,R,B)[l,(j-1)%3,r,b]
// Each (l,j) slab is a contiguous run of R*B floats -> permuted memcpy.
// src slab offset relative to dst slab: j==0 -> +2 slabs, j==1,2 -> -1 slab.

typedef float f4 __attribute__((ext_vector_type(4)));

constexpr int DIMQ    = 3;
constexpr int LBLK    = 27;               // 3^3
constexpr int RBLK    = 59049;            // 3^10
constexpr int BATCH   = 8;
constexpr int CHUNK_F = RBLK * BATCH;     // 472392 floats per (l,j) slab
constexpr int CHUNK_V = CHUNK_F / 4;      // 118098 float4 per slab (16B-aligned)
constexpr int NCHUNK  = LBLK * DIMQ;      // 81 slabs

constexpr int BLOCK  = 256;
constexpr int UNROLL = 4;
constexpr int TILE   = BLOCK * UNROLL;                    // 1024 float4 per block
constexpr int GX     = (CHUNK_V + TILE - 1) / TILE;       // 116

__global__ __launch_bounds__(BLOCK) void xgate_roll_kernel(
        const f4* __restrict__ in, f4* __restrict__ out) {
    const int chunk = blockIdx.y;                 // destination slab index
    const int j = chunk % 3;                      // wave-uniform (scalar unit)
    const int dst_base = chunk * CHUNK_V;
    const int src_base = dst_base + (j == 0 ? 2 * CHUNK_V : -CHUNK_V);

    const int v0 = blockIdx.x * TILE + (int)threadIdx.x;

    if (v0 + (UNROLL - 1) * BLOCK < CHUNK_V) {    // full tile: 4 independent 16B streams
        f4 r[UNROLL];
#pragma unroll
        for (int k = 0; k < UNROLL; ++k)
            r[k] = __builtin_nontemporal_load(&in[src_base + v0 + k * BLOCK]);
#pragma unroll
        for (int k = 0; k < UNROLL; ++k)
            __builtin_nontemporal_store(r[k], &out[dst_base + v0 + k * BLOCK]);
    } else {                                      // tail of the slab
#pragma unroll
        for (int k = 0; k < UNROLL; ++k) {
            const int v = v0 + k * BLOCK;
            if (v < CHUNK_V) {
                f4 r = __builtin_nontemporal_load(&in[src_base + v]);
                __builtin_nontemporal_store(r, &out[dst_base + v]);
            }
        }
    }
}

extern "C" void kernel_launch(void* const* d_in, const int* in_sizes, int n_in,
                              void* d_out, int out_size, void* d_ws, size_t ws_size,
                              hipStream_t stream) {
    const f4* x = (const f4*)d_in[0];
    f4* out = (f4*)d_out;
    dim3 block(BLOCK);
    dim3 grid(GX, NCHUNK);
    xgate_roll_kernel<<<grid, block, 0, stream>>>(x, out);
}